// Round 9
// baseline (249.744 us; speedup 1.0000x reference)
//
#include <hip/hip_runtime.h>

constexpr int BATCH = 2048;
constexpr int NHID  = 512;
constexpr int H0    = 256;
constexpr int H1    = 256;
constexpr int KCH   = 8;            // depth chunks (split-K)
constexpr int DCH   = NHID / KCH;   // 64 rows per chunk
constexpr int S     = 8;            // samples per wave tile
constexpr int LSTRIDE = 2048;

// ws: list int[256][2048] (2MB) | nval int[256] (+pad to 4KB) |
//     wstop float[2048][8][256] (16.8MB) | wsbot float[2048][8][256] (16.8MB)

// ---- kernel 1: per-parent sample lists (R4-verified ballot prefix scan)
__global__ __launch_bounds__(256) void k_prep(const int* __restrict__ parents,
                                              int* __restrict__ list,
                                              int* __restrict__ nval) {
    const int p = blockIdx.x, t = threadIdx.x, g = t >> 6, l = t & 63;
    __shared__ int wcnt[4];
    int running = 0;
    for (int c = 0; c < BATCH; c += 256) {
        const bool match = (parents[c + t] == p);
        const unsigned long long mask = __ballot(match);
        if (l == 0) wcnt[g] = __popcll(mask);
        __syncthreads();
        int off = running;
        for (int w = 0; w < g; ++w) off += wcnt[w];
        if (match)
            list[p * LSTRIDE + off + __popcll(mask & ((1ull << l) - 1ull))] = c + t;
        running += wcnt[0] + wcnt[1] + wcnt[2] + wcnt[3];
        __syncthreads();
    }
    if (t == 0) nval[p] = running;
}

// ---- per-wave chunk GEMV: 64 rows (stride 256), 4 classes/lane, 8 samples.
//      Batch-of-8 named loads (8KB in flight) then 256 FMA; xs in LDS
//      (wave-uniform broadcast reads), no cross-wave traffic, no barriers.
__device__ __forceinline__ void chunk_gemv(const float* __restrict__ W,
                                           const float* __restrict__ xw, // [S][DCH]
                                           int l, float4 acc[S]) {
    for (int d = 0; d < DCH; d += 8) {
        float4 wt[8];
        #pragma unroll
        for (int r = 0; r < 8; ++r)
            wt[r] = *(const float4*)(W + (size_t)(d + r) * 256 + 4 * l);
        #pragma unroll
        for (int r = 0; r < 8; ++r) {
            #pragma unroll
            for (int s = 0; s < S; ++s) {
                const float xv = xw[s * DCH + d + r];   // LDS broadcast
                acc[s].x = fmaf(xv, wt[r].x, acc[s].x);
                acc[s].y = fmaf(xv, wt[r].y, acc[s].y);
                acc[s].z = fmaf(xv, wt[r].z, acc[s].z);
                acc[s].w = fmaf(xv, wt[r].w, acc[s].w);
            }
        }
    }
}

// ---- kernel 2: split-K partial logits. 4 independent waves per block.
//      unit u = bid*4 + wave; u<2048: bottom (p=u>>3, k=u&7, loop n/8 tiles);
//      else: top (j=(u-2048)>>3 -> samples 8j..8j+7, k=&7). No barriers.
__global__ __launch_bounds__(256) void k_gemv(
    const float* __restrict__ x, const float* __restrict__ topW,
    const float* __restrict__ botW, const int* __restrict__ list,
    const int* __restrict__ nval, float* __restrict__ wstop,
    float* __restrict__ wsbot) {
    const int w = threadIdx.x >> 6, l = threadIdx.x & 63;
    const int u = blockIdx.x * 4 + w;
    __shared__ __align__(16) float xs[4][S][DCH];   // 8 KB
    __shared__ int sid[4][S];
    float* xw = &xs[w][0][0];

    if (u < H0 * KCH) {                 // ---- bottom
        const int p = u >> 3, k = u & 7;
        const int n = nval[p];
        const float* W = botW + ((size_t)p * NHID + (size_t)k * DCH) * H1;
        for (int tb = 0; tb < n; tb += S) {
            const int rem = min(S, n - tb);
            if (l < S) sid[w][l] = list[p * LSTRIDE + tb + min(l, rem - 1)];
            // stage 8 samples x 64 floats (128 float4, 2 iters/lane)
            #pragma unroll
            for (int i0 = 0; i0 < 2; ++i0) {
                const int i = i0 * 64 + l, s = i >> 4, c = i & 15;
                const int row = list[p * LSTRIDE + tb + min(s, rem - 1)];
                *(float4*)&xs[w][s][4 * c] =
                    *(const float4*)(x + (size_t)row * NHID + k * DCH + 4 * c);
            }
            float4 acc[S];
            #pragma unroll
            for (int s = 0; s < S; ++s) acc[s] = make_float4(0.f, 0.f, 0.f, 0.f);
            chunk_gemv(W, xw, l, acc);
            for (int s = 0; s < rem; ++s)
                *(float4*)(wsbot + ((size_t)sid[w][s] * KCH + k) * H1 + 4 * l) = acc[s];
        }
    } else {                            // ---- top
        const int u2 = u - H0 * KCH;
        const int j = u2 >> 3, k = u2 & 7;   // samples 8j..8j+7
        const float* W = topW + (size_t)k * DCH * H0;
        #pragma unroll
        for (int i0 = 0; i0 < 2; ++i0) {
            const int i = i0 * 64 + l, s = i >> 4, c = i & 15;
            *(float4*)&xs[w][s][4 * c] =
                *(const float4*)(x + (size_t)(S * j + s) * NHID + k * DCH + 4 * c);
        }
        float4 acc[S];
        #pragma unroll
        for (int s = 0; s < S; ++s) acc[s] = make_float4(0.f, 0.f, 0.f, 0.f);
        chunk_gemv(W, xw, l, acc);
        #pragma unroll
        for (int s = 0; s < S; ++s)
            *(float4*)(wstop + ((size_t)(S * j + s) * KCH + k) * H0 + 4 * l) = acc[s];
    }
}

// ---- kernel 3: chunk-sum + bias + wave softmax (R8-verified) + combine.
//      4 waves/block, wave handles sample s = bid*4 + wave.
__global__ __launch_bounds__(256) void k_fin(
    const int* __restrict__ labels, const int* __restrict__ parents,
    const float* __restrict__ topb, const float* __restrict__ botb,
    const float* __restrict__ wstop, const float* __restrict__ wsbot,
    float* __restrict__ out) {
    const int w = threadIdx.x >> 6, l = threadIdx.x & 63;
    const int s = blockIdx.x * 4 + w;
    const int par = parents[s];
    float pr[2];
    #pragma unroll
    for (int pass = 0; pass < 2; ++pass) {
        const float* wsrc = pass ? wsbot : wstop;
        float4 v = make_float4(0.f, 0.f, 0.f, 0.f);
        #pragma unroll
        for (int k = 0; k < KCH; ++k) {   // fixed order: deterministic
            const float4 c = *(const float4*)(wsrc + ((size_t)s * KCH + k) * 256 + 4 * l);
            v.x += c.x; v.y += c.y; v.z += c.z; v.w += c.w;
        }
        const float4 bias = pass ? *(const float4*)(botb + (size_t)par * H1 + 4 * l)
                                 : *(const float4*)(topb + 4 * l);
        v.x += bias.x; v.y += bias.y; v.z += bias.z; v.w += bias.w;

        float m = fmaxf(fmaxf(v.x, v.y), fmaxf(v.z, v.w));
        #pragma unroll
        for (int off = 32; off > 0; off >>= 1)
            m = fmaxf(m, __shfl_xor(m, off, 64));

        const float ex = expf(v.x - m), ey = expf(v.y - m);
        const float ez = expf(v.z - m), ew = expf(v.w - m);
        float sum = (ex + ey) + (ez + ew);
        #pragma unroll
        for (int off = 32; off > 0; off >>= 1)
            sum += __shfl_xor(sum, off, 64);

        const int tgt = pass ? labels[s] : par;
        const int c0 = 4 * l;
        float et = (c0 == tgt) ? ex : (c0 + 1 == tgt) ? ey
                 : (c0 + 2 == tgt) ? ez : (c0 + 3 == tgt) ? ew : 0.f;
        #pragma unroll
        for (int off = 32; off > 0; off >>= 1)
            et += __shfl_xor(et, off, 64);

        pr[pass] = et / sum;
    }
    if (l == 0) out[s] = pr[0] * pr[1];
}

extern "C" void kernel_launch(void* const* d_in, const int* in_sizes, int n_in,
                              void* d_out, int out_size, void* d_ws, size_t ws_size,
                              hipStream_t stream) {
    const float* x       = (const float*)d_in[0];
    const int*   labels  = (const int*)  d_in[1];
    const int*   parents = (const int*)  d_in[2];
    const float* topW    = (const float*)d_in[3];
    const float* topb    = (const float*)d_in[4];
    const float* botW    = (const float*)d_in[5];
    const float* botb    = (const float*)d_in[6];
    float*       out     = (float*)d_out;

    int*   list  = (int*)d_ws;
    int*   nval  = (int*)((char*)d_ws + (size_t)H0 * LSTRIDE * sizeof(int));
    float* wstop = (float*)((char*)d_ws + (size_t)H0 * LSTRIDE * sizeof(int) + 4096);
    float* wsbot = wstop + (size_t)BATCH * KCH * H0;

    k_prep<<<H0, 256, 0, stream>>>(parents, list, nval);
    const int units = H0 * KCH + (BATCH / S) * KCH;   // 2048 + 2048
    k_gemv<<<units / 4, 256, 0, stream>>>(x, topW, botW, list, nval, wstop, wsbot);
    k_fin<<<BATCH / 4, 256, 0, stream>>>(labels, parents, topb, botb, wstop, wsbot, out);
}